// Round 15
// baseline (182.828 us; speedup 1.0000x reference)
//
#include <hip/hip_runtime.h>
#include <hip/hip_bf16.h>
#include <math.h>

#define BB 8
#define SS 160
#define HH 768
#define DEPTH 64
#define NHEAD 12
#define DHEAD 64
#define BS (BB*SS)
#define SCROW (NHEAD*SS)   // 1920 f16 per (b,i) row

constexpr float EPS_C = 1e-5f;

typedef __attribute__((ext_vector_type(8))) short bf16x8;
typedef __attribute__((ext_vector_type(4))) float f32x4;

__device__ inline short f2bs(float x) {
    union { __hip_bfloat16 b; short s; } u;
    u.b = __float2bfloat16(x);
    return u.s;
}

// ---------------- MFMA GEMM: {q,k,v} = X @ W + b (R14-proven) --------------
__global__ __launch_bounds__(256) void gemm_qkv(
    const float* __restrict__ X,
    const float* __restrict__ Wq, const float* __restrict__ Wk,
    const float* __restrict__ Wv,
    const float* __restrict__ bq, const float* __restrict__ bk,
    const float* __restrict__ bv,
    __hip_bfloat16* __restrict__ qb, __hip_bfloat16* __restrict__ kb,
    __hip_bfloat16* __restrict__ vb)
{
    __shared__ int4 sA[4][128];   // 8 KB
    __shared__ int4 sB[4][64];    // 4 KB
    int m0 = blockIdx.x * 128, n0 = blockIdx.y * 64, mat = blockIdx.z;
    const float* W    = (mat == 0) ? Wq : (mat == 1) ? Wk : Wv;
    const float* bias = (mat == 0) ? bq : (mat == 1) ? bk : bv;
    int tid = threadIdx.x, w = tid >> 6, l = tid & 63;
    int wm = (w >> 1) * 64, wn = (w & 1) * 32;
    int khalf = l >> 4, lc = l & 15;

    f32x4 acc[4][2];
#pragma unroll
    for (int i = 0; i < 4; i++)
#pragma unroll
        for (int j = 0; j < 2; j++) acc[i][j] = (f32x4){0.f, 0.f, 0.f, 0.f};

    for (int k0 = 0; k0 < HH; k0 += 32) {
        __syncthreads();
#pragma unroll
        for (int rr = 0; rr < 2; rr++) {
            const float* ap = X + (size_t)(m0 + l + rr * 64) * HH + k0 + w * 8;
            float4 x0 = *(const float4*)ap;
            float4 x1 = *(const float4*)(ap + 4);
            bf16x8 p;
            p[0]=f2bs(x0.x); p[1]=f2bs(x0.y); p[2]=f2bs(x0.z); p[3]=f2bs(x0.w);
            p[4]=f2bs(x1.x); p[5]=f2bs(x1.y); p[6]=f2bs(x1.z); p[7]=f2bs(x1.w);
            *(bf16x8*)&sA[w][l + rr * 64] = p;
        }
        {
            const float* wp = W + (size_t)(k0 + w * 8) * HH + n0 + l;
            bf16x8 p;
#pragma unroll
            for (int i = 0; i < 8; i++) p[i] = f2bs(wp[(size_t)i * HH]);
            *(bf16x8*)&sB[w][l] = p;
        }
        __syncthreads();
        bf16x8 b0 = *(const bf16x8*)&sB[khalf][wn + lc];
        bf16x8 b1 = *(const bf16x8*)&sB[khalf][wn + 16 + lc];
#pragma unroll
        for (int mi = 0; mi < 4; mi++) {
            bf16x8 a = *(const bf16x8*)&sA[khalf][wm + mi * 16 + lc];
            acc[mi][0] = __builtin_amdgcn_mfma_f32_16x16x32_bf16(a, b0, acc[mi][0], 0, 0, 0);
            acc[mi][1] = __builtin_amdgcn_mfma_f32_16x16x32_bf16(a, b1, acc[mi][1], 0, 0, 0);
        }
    }

    int rg = (l >> 4) * 4;
    __hip_bfloat16* outm = (mat == 0) ? qb : (mat == 1) ? kb : vb;
#pragma unroll
    for (int ni = 0; ni < 2; ni++) {
        int gcol = n0 + wn + ni * 16 + lc;
        float bv_ = bias[gcol];
#pragma unroll
        for (int mi = 0; mi < 4; mi++) {
            int grow = m0 + wm + mi * 16 + rg;
            f32x4 a = acc[mi][ni];
            __hip_bfloat16* o = outm + (size_t)grow * HH + gcol;
            o[0]      = __float2bfloat16(a.x + bv_);
            o[HH]     = __float2bfloat16(a.y + bv_);
            o[2 * HH] = __float2bfloat16(a.z + bv_);
            o[3 * HH] = __float2bfloat16(a.w + bv_);
        }
    }
}

// ---------------- MFMA scores -> sc[b][i][h][j] (f16) (R14-proven) ----------
__global__ __launch_bounds__(256) void scores_gemm(
    const __hip_bfloat16* __restrict__ qb, const __hip_bfloat16* __restrict__ kb,
    _Float16* __restrict__ sc)
{
    __shared__ int4 sQ[8][160];   // 20.5 KB
    __shared__ int4 sK[8][160];
    int h = blockIdx.x, b = blockIdx.y;
    const short* Q = (const short*)qb + (size_t)b * SS * HH + h * DHEAD;
    const short* K = (const short*)kb + (size_t)b * SS * HH + h * DHEAD;
    int tid = threadIdx.x, w = tid >> 6, l = tid & 63;

    for (int idx = tid; idx < SS * 8; idx += 256) {
        int row = idx >> 3, ch = idx & 7;
        sQ[ch][row] = *(const int4*)(Q + (size_t)row * HH + ch * 8);
        sK[ch][row] = *(const int4*)(K + (size_t)row * HH + ch * 8);
    }
    __syncthreads();

    int wm = (w >> 1) * 80, wn = (w & 1) * 80;
    int khalf = l >> 4, lc = l & 15;
    f32x4 acc[5][5];
#pragma unroll
    for (int i = 0; i < 5; i++)
#pragma unroll
        for (int j = 0; j < 5; j++) acc[i][j] = (f32x4){0.f, 0.f, 0.f, 0.f};

#pragma unroll
    for (int s = 0; s < 2; s++) {
        int c = s * 4 + khalf;
        bf16x8 bf[5];
#pragma unroll
        for (int ni = 0; ni < 5; ni++)
            bf[ni] = *(const bf16x8*)&sK[c][wn + ni * 16 + lc];
#pragma unroll
        for (int mi = 0; mi < 5; mi++) {
            bf16x8 a = *(const bf16x8*)&sQ[c][wm + mi * 16 + lc];
#pragma unroll
            for (int ni = 0; ni < 5; ni++)
                acc[mi][ni] = __builtin_amdgcn_mfma_f32_16x16x32_bf16(a, bf[ni], acc[mi][ni], 0, 0, 0);
        }
    }

    int rg = (l >> 4) * 4;
    _Float16* base = sc + ((size_t)b * SS) * SCROW + (size_t)h * SS;
#pragma unroll
    for (int mi = 0; mi < 5; mi++) {
        int i0 = wm + mi * 16 + rg;
#pragma unroll
        for (int ni = 0; ni < 5; ni++) {
            int j = wn + ni * 16 + lc;
            f32x4 a = acc[mi][ni];
            base[(size_t)(i0 + 0) * SCROW + j] = (_Float16)(a.x * 0.125f);
            base[(size_t)(i0 + 1) * SCROW + j] = (_Float16)(a.y * 0.125f);
            base[(size_t)(i0 + 2) * SCROW + j] = (_Float16)(a.z * 0.125f);
            base[(size_t)(i0 + 3) * SCROW + j] = (_Float16)(a.w * 0.125f);
        }
    }
}

// ---------------- qek_slim (R14-proven) --------------------------------------
__global__ __launch_bounds__(256) void qek_slim(
    const __hip_bfloat16* __restrict__ qb, const float* __restrict__ Wek,
    __hip_bfloat16* __restrict__ qek)
{
    __shared__ short sW[8 * 65 * 8];   // 8.1 KB
    int h = blockIdx.x, mg = blockIdx.y;
    int tid = threadIdx.x, w = tid >> 6, l = tid & 63;
    int lr = l & 15, kg = l >> 4;

    {
        int d = tid >> 2, q4 = tid & 3;
        const float* wp = Wek + (size_t)d * HH + h * DHEAD + q4 * 16;
        float4 w0 = *(const float4*)(wp);
        float4 w1 = *(const float4*)(wp + 4);
        float4 w2 = *(const float4*)(wp + 8);
        float4 w3 = *(const float4*)(wp + 12);
        bf16x8 p0, p1;
        p0[0]=f2bs(w0.x); p0[1]=f2bs(w0.y); p0[2]=f2bs(w0.z); p0[3]=f2bs(w0.w);
        p0[4]=f2bs(w1.x); p0[5]=f2bs(w1.y); p0[6]=f2bs(w1.z); p0[7]=f2bs(w1.w);
        p1[0]=f2bs(w2.x); p1[1]=f2bs(w2.y); p1[2]=f2bs(w2.z); p1[3]=f2bs(w2.w);
        p1[4]=f2bs(w3.x); p1[5]=f2bs(w3.y); p1[6]=f2bs(w3.z); p1[7]=f2bs(w3.w);
        *(bf16x8*)&sW[((q4 * 2) * 65 + d) * 8]     = p0;
        *(bf16x8*)&sW[((q4 * 2 + 1) * 65 + d) * 8] = p1;
    }
    __syncthreads();

    bf16x8 bfrag[2][4];
#pragma unroll
    for (int s = 0; s < 2; s++)
#pragma unroll
        for (int nt = 0; nt < 4; nt++)
            bfrag[s][nt] = *(const bf16x8*)&sW[((s * 4 + kg) * 65 + nt * 16 + lr) * 8];

    const short* Q = (const short*)qb;
    short* O = (short*)qek;
    int m0 = (mg * 4 + w) * 16;
    bf16x8 a0 = *(const bf16x8*)(Q + (size_t)(m0 + lr) * HH + h * DHEAD + kg * 8);
    bf16x8 a1 = *(const bf16x8*)(Q + (size_t)(m0 + lr) * HH + h * DHEAD + 32 + kg * 8);
#pragma unroll
    for (int nt = 0; nt < 4; nt++) {
        f32x4 acc = (f32x4){0.f, 0.f, 0.f, 0.f};
        acc = __builtin_amdgcn_mfma_f32_16x16x32_bf16(a0, bfrag[0][nt], acc, 0, 0, 0);
        acc = __builtin_amdgcn_mfma_f32_16x16x32_bf16(a1, bfrag[1][nt], acc, 0, 0, 0);
        int row0 = m0 + kg * 4;
#pragma unroll
        for (int r = 0; r < 4; r++)
            O[(size_t)(row0 + r) * HH + h * DHEAD + nt * 16 + lr] = f2bs(acc[r]);
    }
}

// ---------------- escore_add2 (R14-proven) -----------------------------------
__global__ __launch_bounds__(256) void escore_add2(
    const float* __restrict__ edge, const __hip_bfloat16* __restrict__ qek,
    _Float16* __restrict__ sc)
{
    int task = blockIdx.x * 4 + (threadIdx.x >> 6);   // 0..6399
    int l = threadIdx.x & 63;
    int bi = task / 5, seg = task - (task / 5) * 5;
    int lr = l & 15, kg = l >> 4;

    const short* QE = (const short*)qek + (size_t)bi * HH;
    bf16x8 qe0 = *(const bf16x8*)(QE + lr * DHEAD + kg * 8);
    bf16x8 qe1 = *(const bf16x8*)(QE + lr * DHEAD + 32 + kg * 8);

    const float* E = edge + (size_t)bi * SS * DEPTH;
    _Float16* srow = sc + (size_t)bi * SCROW;

#pragma unroll
    for (int t = 0; t < 2; t++) {
        int jt = seg * 2 + t;
        const float* ep = E + (size_t)(jt * 16 + lr) * DEPTH + kg * 8;
        float4 e0 = *(const float4*)(ep);
        float4 e1 = *(const float4*)(ep + 4);
        float4 e2 = *(const float4*)(ep + 32);
        float4 e3 = *(const float4*)(ep + 36);
        bf16x8 a0, a1;
        a0[0]=f2bs(e0.x); a0[1]=f2bs(e0.y); a0[2]=f2bs(e0.z); a0[3]=f2bs(e0.w);
        a0[4]=f2bs(e1.x); a0[5]=f2bs(e1.y); a0[6]=f2bs(e1.z); a0[7]=f2bs(e1.w);
        a1[0]=f2bs(e2.x); a1[1]=f2bs(e2.y); a1[2]=f2bs(e2.z); a1[3]=f2bs(e2.w);
        a1[4]=f2bs(e3.x); a1[5]=f2bs(e3.y); a1[6]=f2bs(e3.z); a1[7]=f2bs(e3.w);
        f32x4 acc = (f32x4){0.f, 0.f, 0.f, 0.f};
        acc = __builtin_amdgcn_mfma_f32_16x16x32_bf16(a0, qe0, acc, 0, 0, 0);
        acc = __builtin_amdgcn_mfma_f32_16x16x32_bf16(a1, qe1, acc, 0, 0, 0);
        if (lr < NHEAD) {
            int j0 = jt * 16 + kg * 4;
            _Float16* p = srow + (size_t)lr * SS + j0;
#pragma unroll
            for (int r = 0; r < 4; r++)
                p[r] = (_Float16)((float)p[r] + 0.125f * acc[r]);
        }
    }
}

// ---------------- pv_soft: per (b,h): softmax rows then ctx_v = P @ V_h ------
// Stage masked scores (f16) + V^T (bf16) in LDS; softmax in-block; PV via MFMA.
__global__ __launch_bounds__(256) void pv_soft(
    const __hip_bfloat16* __restrict__ qb, const __hip_bfloat16* __restrict__ vb,
    const float* __restrict__ bek, const int* __restrict__ mask,
    const _Float16* __restrict__ sc, __hip_bfloat16* __restrict__ ctxv)
{
    __shared__ alignas(16) short sS[SS][168];      // scores f16 -> probs bf16
    __shared__ alignas(16) short sVT[DHEAD][168];  // V^T bf16
    __shared__ float s_qbek_i[SS];
    int h = blockIdx.x, b = blockIdx.y;
    int tid = threadIdx.x, w = tid >> 6, l = tid & 63;
    int lr = l & 15, kg = l >> 4;

    // qbek per row i
    if (tid < SS) {
        const __hip_bfloat16* qp = qb + (size_t)(b * SS + tid) * HH + h * DHEAD;
        const float* bp = bek + h * DHEAD;
        float s = 0.f;
#pragma unroll 8
        for (int c = 0; c < DHEAD; c++) s += __bfloat162float(qp[c]) * bp[c];
        s_qbek_i[tid] = s;
    }
    // stage V^T (coalesced global read, transposed LDS write)
    const short* V = (const short*)vb;
    for (int idx = tid; idx < SS * DHEAD; idx += 256) {
        int j = idx >> 6, c = idx & 63;
        sVT[c][j] = V[(size_t)(b * SS + j) * HH + h * DHEAD + c];
    }
    __syncthreads();

    // stage masked scores as f16
    const _Float16* scb = sc + (size_t)b * SS * SCROW + h * SS;
    const int* mrow = mask + (size_t)b * SS * SS;
    for (int idx = tid; idx < SS * SS; idx += 256) {
        int i = idx / SS, j = idx - i * SS;
        float s = mrow[i * SS + j]
                ? ((float)scb[(size_t)i * SCROW + j] + 0.125f * s_qbek_i[i])
                : -10000.f;
        _Float16 hv = (_Float16)s;
        sS[i][j] = *(short*)&hv;
    }
    __syncthreads();

    // row softmax; write probs back as bf16
    for (int r = w; r < SS; r += 4) {
        _Float16* row = (_Float16*)&sS[r][0];
        float v0 = (float)row[l];
        float v1 = (float)row[l + 64];
        float v2 = (l < 32) ? (float)row[l + 128] : -INFINITY;
        float mx = fmaxf(v0, fmaxf(v1, v2));
#pragma unroll
        for (int mm = 32; mm >= 1; mm >>= 1) mx = fmaxf(mx, __shfl_xor(mx, mm, 64));
        float e0 = expf(v0 - mx), e1 = expf(v1 - mx);
        float e2 = (l < 32) ? expf(v2 - mx) : 0.f;
        float sm = e0 + e1 + e2;
#pragma unroll
        for (int mm = 32; mm >= 1; mm >>= 1) sm += __shfl_xor(sm, mm, 64);
        float inv = 1.0f / sm;
        sS[r][l]      = f2bs(e0 * inv);
        sS[r][l + 64] = f2bs(e1 * inv);
        if (l < 32) sS[r][l + 128] = f2bs(e2 * inv);
    }
    __syncthreads();

    // PV MFMA: wave = 80(i) x 32(c) tile; K = 160(j) in 5 steps
    int wm = (w >> 1) * 80, wn = (w & 1) * 32;
    f32x4 acc[5][2];
#pragma unroll
    for (int i = 0; i < 5; i++)
#pragma unroll
        for (int j = 0; j < 2; j++) acc[i][j] = (f32x4){0.f, 0.f, 0.f, 0.f};

#pragma unroll
    for (int s = 0; s < 5; s++) {
        int k0 = s * 32 + kg * 8;
        bf16x8 b0 = *(const bf16x8*)&sVT[wn + lr][k0];
        bf16x8 b1 = *(const bf16x8*)&sVT[wn + 16 + lr][k0];
#pragma unroll
        for (int mi = 0; mi < 5; mi++) {
            bf16x8 a = *(const bf16x8*)&sS[wm + mi * 16 + lr][k0];
            acc[mi][0] = __builtin_amdgcn_mfma_f32_16x16x32_bf16(a, b0, acc[mi][0], 0, 0, 0);
            acc[mi][1] = __builtin_amdgcn_mfma_f32_16x16x32_bf16(a, b1, acc[mi][1], 0, 0, 0);
        }
    }

    // write ctx_v bf16 [bi][h*64+c]
    short* cv = (short*)ctxv;
    int rg = kg * 4;
#pragma unroll
    for (int ni = 0; ni < 2; ni++) {
        int c = wn + ni * 16 + lr;
#pragma unroll
        for (int mi = 0; mi < 5; mi++) {
            int i0 = wm + mi * 16 + rg;
            f32x4 a = acc[mi][ni];
#pragma unroll
            for (int r = 0; r < 4; r++)
                cv[(size_t)(b * SS + i0 + r) * HH + h * DHEAD + c] = f2bs(a[r]);
        }
    }
}

// ---------------- final_ln: per (b,i): softmax + pe(MFMA) + Wev + LN ---------
__global__ __launch_bounds__(256) void final_ln(
    const float* __restrict__ token, const float* __restrict__ edge,
    const int* __restrict__ mask,
    const __hip_bfloat16* __restrict__ q_ws, const _Float16* __restrict__ sc,
    const __hip_bfloat16* __restrict__ ctxv,
    const float* __restrict__ bek,
    const float* __restrict__ Wev, const float* __restrict__ bev,
    const float* __restrict__ ln_g, const float* __restrict__ ln_b,
    float* __restrict__ out)
{
    __shared__ float  s_scores[NHEAD][SS + 2]; // padded stride 162
    __shared__ float  s_pe[NHEAD][DEPTH];
    __shared__ float  s_x[HH];
    __shared__ float  s_qbek[NHEAD];
    __shared__ int    s_mask[SS];
    __shared__ float  s_red[8];

    int bi = blockIdx.x;
    int tid = threadIdx.x;
    int w = tid >> 6, l = tid & 63;
    int lr = l & 15, kg = l >> 4;

    if (tid < SS) s_mask[tid] = mask[(size_t)bi * SS + tid];

    // qbek: 16-lane cooperative dot
    {
        int hs = w * 3 + kg;
        float part = 0.f;
        if (hs < NHEAD) {
            const __hip_bfloat16* qp = q_ws + (size_t)bi * HH + hs * DHEAD + lr * 4;
            float4 bv4 = *(const float4*)(bek + hs * DHEAD + lr * 4);
            part = __bfloat162float(qp[0]) * bv4.x + __bfloat162float(qp[1]) * bv4.y
                 + __bfloat162float(qp[2]) * bv4.z + __bfloat162float(qp[3]) * bv4.w;
        }
        part += __shfl_xor(part, 1, 64);
        part += __shfl_xor(part, 2, 64);
        part += __shfl_xor(part, 4, 64);
        part += __shfl_xor(part, 8, 64);
        if (lr == 0 && hs < NHEAD) s_qbek[hs] = part;
    }
    __syncthreads();

    // assemble scores (linear coalesced f16 reads)
    const _Float16* scrow = sc + (size_t)bi * SCROW;
    for (int idx = tid; idx < NHEAD * SS; idx += 256) {
        int h = idx / SS, j = idx - h * SS;
        float qk = (float)scrow[idx];
        s_scores[h][j] = s_mask[j] ? (qk + 0.125f * s_qbek[h]) : -10000.0f;
    }
    __syncthreads();

    // softmax per head
    for (int h = w; h < NHEAD; h += 4) {
        float v0 = s_scores[h][l];
        float v1 = s_scores[h][l + 64];
        float v2 = (l < 32) ? s_scores[h][l + 128] : -INFINITY;
        float mx = fmaxf(v0, fmaxf(v1, v2));
#pragma unroll
        for (int mm = 32; mm >= 1; mm >>= 1) mx = fmaxf(mx, __shfl_xor(mx, mm, 64));
        float e0 = expf(v0 - mx), e1 = expf(v1 - mx);
        float e2 = (l < 32) ? expf(v2 - mx) : 0.f;
        float sm = e0 + e1 + e2;
#pragma unroll
        for (int mm = 32; mm >= 1; mm >>= 1) sm += __shfl_xor(sm, mm, 64);
        float inv = 1.0f / sm;
        s_scores[h][l]      = e0 * inv;
        s_scores[h][l + 64] = e1 * inv;
        if (l < 32) s_scores[h][l + 128] = e2 * inv;
    }
    __syncthreads();

    // pe[h][d] = sum_j P[h][j] E[j][d] via MFMA; wave w -> d-tile [w*16, w*16+16)
    {
        int arow = (lr < NHEAD) ? lr : (NHEAD - 1);   // clamp pad rows
        const float* Eb = edge + (size_t)bi * SS * DEPTH;
        int d = w * 16 + lr;
        f32x4 acc = (f32x4){0.f, 0.f, 0.f, 0.f};
#pragma unroll
        for (int s = 0; s < 5; s++) {
            int k0 = s * 32 + kg * 8;
            bf16x8 a, bfr;
#pragma unroll
            for (int e = 0; e < 8; e++) a[e] = f2bs(s_scores[arow][k0 + e]);
#pragma unroll
            for (int e = 0; e < 8; e++)
                bfr[e] = f2bs(Eb[(size_t)(k0 + e) * DEPTH + d]);
            acc = __builtin_amdgcn_mfma_f32_16x16x32_bf16(a, bfr, acc, 0, 0, 0);
        }
#pragma unroll
        for (int r = 0; r < 4; r++) {
            int h = kg * 4 + r;
            if (h < NHEAD) s_pe[h][d] = acc[r];
        }
    }
    __syncthreads();

    // ctx_e = pe_h @ Wev_h + bev ; + ctx_v + token -> s_x
    for (int mdx = tid; mdx < HH; mdx += 256) {
        int h = mdx >> 6;
        const float* pep = &s_pe[h][0];
        float sum = 0.f;
#pragma unroll
        for (int d = 0; d < DEPTH; d++) sum += pep[d] * Wev[(size_t)d * HH + mdx];
        float cvv = __bfloat162float(ctxv[(size_t)bi * HH + mdx]);
        s_x[mdx] = token[(size_t)bi * HH + mdx] + cvv + sum + bev[mdx];
    }
    __syncthreads();

    // LayerNorm
    float lsum = 0.f, lsq = 0.f;
    for (int c = tid; c < HH; c += 256) {
        float x = s_x[c];
        lsum += x; lsq += x * x;
    }
#pragma unroll
    for (int mm = 32; mm >= 1; mm >>= 1) {
        lsum += __shfl_xor(lsum, mm, 64);
        lsq  += __shfl_xor(lsq,  mm, 64);
    }
    if (l == 0) { s_red[w] = lsum; s_red[4 + w] = lsq; }
    __syncthreads();
    float tsum = s_red[0] + s_red[1] + s_red[2] + s_red[3];
    float tsq  = s_red[4] + s_red[5] + s_red[6] + s_red[7];
    float mu  = tsum / HH;
    float var = tsq / HH - mu * mu;
    float rstd = rsqrtf(var + EPS_C);
    for (int c = tid; c < HH; c += 256)
        out[(size_t)bi * HH + c] = (s_x[c] - mu) * rstd * ln_g[c] + ln_b[c];
}

extern "C" void kernel_launch(void* const* d_in, const int* in_sizes, int n_in,
                              void* d_out, int out_size, void* d_ws, size_t ws_size,
                              hipStream_t stream) {
    const float* token = (const float*)d_in[0];
    const float* edge  = (const float*)d_in[1];
    const int*   mask  = (const int*)d_in[2];
    const float* Wq = (const float*)d_in[3];  const float* bq = (const float*)d_in[4];
    const float* Wk = (const float*)d_in[5];  const float* bk = (const float*)d_in[6];
    const float* Wv = (const float*)d_in[7];  const float* bv = (const float*)d_in[8];
    const float* Wek = (const float*)d_in[9];  const float* bek = (const float*)d_in[10];
    const float* Wev = (const float*)d_in[11]; const float* bev = (const float*)d_in[12];
    const float* ln_g = (const float*)d_in[13]; const float* ln_b = (const float*)d_in[14];
    float* out = (float*)d_out;

    // ws layout (10.31 MiB, proven): [qb][kb][vb][sc]
    // qek (1.875 MiB) aliases kb after scores_gemm (kb dead then);
    // ctxv bf16 (1.875 MiB) aliases the same region after escore_add2 (qek dead).
    __hip_bfloat16* qb = (__hip_bfloat16*)d_ws;
    __hip_bfloat16* kb = qb + (size_t)BS * HH;
    __hip_bfloat16* vb = kb + (size_t)BS * HH;
    _Float16*       sc = (_Float16*)(vb + (size_t)BS * HH);
    __hip_bfloat16* qek  = kb;
    __hip_bfloat16* ctxv = kb;

    gemm_qkv<<<dim3(BS / 128, HH / 64, 3), 256, 0, stream>>>(
        token, Wq, Wk, Wv, bq, bk, bv, qb, kb, vb);
    scores_gemm<<<dim3(NHEAD, BB), 256, 0, stream>>>(qb, kb, sc);
    qek_slim<<<dim3(NHEAD, 20), 256, 0, stream>>>(qb, Wek, qek);
    escore_add2<<<1600, 256, 0, stream>>>(edge, qek, sc);
    pv_soft<<<dim3(NHEAD, BB), 256, 0, stream>>>(qb, vb, bek, mask, sc, ctxv);
    final_ln<<<BS, 256, 0, stream>>>(token, edge, mask, qb, sc, ctxv,
                                     bek, Wev, bev, ln_g, ln_b, out);
}

// Round 16
// 113.143 us; speedup vs baseline: 1.6159x; 1.6159x over previous
//
#include <hip/hip_runtime.h>
#include <hip/hip_bf16.h>
#include <math.h>

#define BB 8
#define SS 160
#define HH 768
#define DEPTH 64
#define NHEAD 12
#define DHEAD 64
#define BS (BB*SS)
#define SCROW (NHEAD*SS)   // 1920 f16 per (b,i) row

constexpr float EPS_C = 1e-5f;

typedef __attribute__((ext_vector_type(8))) short bf16x8;
typedef __attribute__((ext_vector_type(4))) float f32x4;

__device__ inline short f2bs(float x) {
    union { __hip_bfloat16 b; short s; } u;
    u.b = __float2bfloat16(x);
    return u.s;
}

// ---------------- MFMA GEMM: {q,k,v} = X @ W + b (R14-proven) --------------
__global__ __launch_bounds__(256) void gemm_qkv(
    const float* __restrict__ X,
    const float* __restrict__ Wq, const float* __restrict__ Wk,
    const float* __restrict__ Wv,
    const float* __restrict__ bq, const float* __restrict__ bk,
    const float* __restrict__ bv,
    __hip_bfloat16* __restrict__ qb, __hip_bfloat16* __restrict__ kb,
    __hip_bfloat16* __restrict__ vb)
{
    __shared__ int4 sA[4][128];   // 8 KB
    __shared__ int4 sB[4][64];    // 4 KB
    int m0 = blockIdx.x * 128, n0 = blockIdx.y * 64, mat = blockIdx.z;
    const float* W    = (mat == 0) ? Wq : (mat == 1) ? Wk : Wv;
    const float* bias = (mat == 0) ? bq : (mat == 1) ? bk : bv;
    int tid = threadIdx.x, w = tid >> 6, l = tid & 63;
    int wm = (w >> 1) * 64, wn = (w & 1) * 32;
    int khalf = l >> 4, lc = l & 15;

    f32x4 acc[4][2];
#pragma unroll
    for (int i = 0; i < 4; i++)
#pragma unroll
        for (int j = 0; j < 2; j++) acc[i][j] = (f32x4){0.f, 0.f, 0.f, 0.f};

    for (int k0 = 0; k0 < HH; k0 += 32) {
        __syncthreads();
#pragma unroll
        for (int rr = 0; rr < 2; rr++) {
            const float* ap = X + (size_t)(m0 + l + rr * 64) * HH + k0 + w * 8;
            float4 x0 = *(const float4*)ap;
            float4 x1 = *(const float4*)(ap + 4);
            bf16x8 p;
            p[0]=f2bs(x0.x); p[1]=f2bs(x0.y); p[2]=f2bs(x0.z); p[3]=f2bs(x0.w);
            p[4]=f2bs(x1.x); p[5]=f2bs(x1.y); p[6]=f2bs(x1.z); p[7]=f2bs(x1.w);
            *(bf16x8*)&sA[w][l + rr * 64] = p;
        }
        {
            const float* wp = W + (size_t)(k0 + w * 8) * HH + n0 + l;
            bf16x8 p;
#pragma unroll
            for (int i = 0; i < 8; i++) p[i] = f2bs(wp[(size_t)i * HH]);
            *(bf16x8*)&sB[w][l] = p;
        }
        __syncthreads();
        bf16x8 b0 = *(const bf16x8*)&sB[khalf][wn + lc];
        bf16x8 b1 = *(const bf16x8*)&sB[khalf][wn + 16 + lc];
#pragma unroll
        for (int mi = 0; mi < 4; mi++) {
            bf16x8 a = *(const bf16x8*)&sA[khalf][wm + mi * 16 + lc];
            acc[mi][0] = __builtin_amdgcn_mfma_f32_16x16x32_bf16(a, b0, acc[mi][0], 0, 0, 0);
            acc[mi][1] = __builtin_amdgcn_mfma_f32_16x16x32_bf16(a, b1, acc[mi][1], 0, 0, 0);
        }
    }

    int rg = (l >> 4) * 4;
    __hip_bfloat16* outm = (mat == 0) ? qb : (mat == 1) ? kb : vb;
#pragma unroll
    for (int ni = 0; ni < 2; ni++) {
        int gcol = n0 + wn + ni * 16 + lc;
        float bv_ = bias[gcol];
#pragma unroll
        for (int mi = 0; mi < 4; mi++) {
            int grow = m0 + wm + mi * 16 + rg;
            f32x4 a = acc[mi][ni];
            __hip_bfloat16* o = outm + (size_t)grow * HH + gcol;
            o[0]      = __float2bfloat16(a.x + bv_);
            o[HH]     = __float2bfloat16(a.y + bv_);
            o[2 * HH] = __float2bfloat16(a.z + bv_);
            o[3 * HH] = __float2bfloat16(a.w + bv_);
        }
    }
}

// ---------------- MFMA scores -> sc[b][i][h][j] (f16) (R14-proven) ----------
__global__ __launch_bounds__(256) void scores_gemm(
    const __hip_bfloat16* __restrict__ qb, const __hip_bfloat16* __restrict__ kb,
    _Float16* __restrict__ sc)
{
    __shared__ int4 sQ[8][160];   // 20.5 KB
    __shared__ int4 sK[8][160];
    int h = blockIdx.x, b = blockIdx.y;
    const short* Q = (const short*)qb + (size_t)b * SS * HH + h * DHEAD;
    const short* K = (const short*)kb + (size_t)b * SS * HH + h * DHEAD;
    int tid = threadIdx.x, w = tid >> 6, l = tid & 63;

    for (int idx = tid; idx < SS * 8; idx += 256) {
        int row = idx >> 3, ch = idx & 7;
        sQ[ch][row] = *(const int4*)(Q + (size_t)row * HH + ch * 8);
        sK[ch][row] = *(const int4*)(K + (size_t)row * HH + ch * 8);
    }
    __syncthreads();

    int wm = (w >> 1) * 80, wn = (w & 1) * 80;
    int khalf = l >> 4, lc = l & 15;
    f32x4 acc[5][5];
#pragma unroll
    for (int i = 0; i < 5; i++)
#pragma unroll
        for (int j = 0; j < 5; j++) acc[i][j] = (f32x4){0.f, 0.f, 0.f, 0.f};

#pragma unroll
    for (int s = 0; s < 2; s++) {
        int c = s * 4 + khalf;
        bf16x8 bf[5];
#pragma unroll
        for (int ni = 0; ni < 5; ni++)
            bf[ni] = *(const bf16x8*)&sK[c][wn + ni * 16 + lc];
#pragma unroll
        for (int mi = 0; mi < 5; mi++) {
            bf16x8 a = *(const bf16x8*)&sQ[c][wm + mi * 16 + lc];
#pragma unroll
            for (int ni = 0; ni < 5; ni++)
                acc[mi][ni] = __builtin_amdgcn_mfma_f32_16x16x32_bf16(a, bf[ni], acc[mi][ni], 0, 0, 0);
        }
    }

    int rg = (l >> 4) * 4;
    _Float16* base = sc + ((size_t)b * SS) * SCROW + (size_t)h * SS;
#pragma unroll
    for (int mi = 0; mi < 5; mi++) {
        int i0 = wm + mi * 16 + rg;
#pragma unroll
        for (int ni = 0; ni < 5; ni++) {
            int j = wn + ni * 16 + lc;
            f32x4 a = acc[mi][ni];
            base[(size_t)(i0 + 0) * SCROW + j] = (_Float16)(a.x * 0.125f);
            base[(size_t)(i0 + 1) * SCROW + j] = (_Float16)(a.y * 0.125f);
            base[(size_t)(i0 + 2) * SCROW + j] = (_Float16)(a.z * 0.125f);
            base[(size_t)(i0 + 3) * SCROW + j] = (_Float16)(a.w * 0.125f);
        }
    }
}

// ---------------- qek_slim (R14-proven) --------------------------------------
__global__ __launch_bounds__(256) void qek_slim(
    const __hip_bfloat16* __restrict__ qb, const float* __restrict__ Wek,
    __hip_bfloat16* __restrict__ qek)
{
    __shared__ short sW[8 * 65 * 8];   // 8.1 KB
    int h = blockIdx.x, mg = blockIdx.y;
    int tid = threadIdx.x, w = tid >> 6, l = tid & 63;
    int lr = l & 15, kg = l >> 4;

    {
        int d = tid >> 2, q4 = tid & 3;
        const float* wp = Wek + (size_t)d * HH + h * DHEAD + q4 * 16;
        float4 w0 = *(const float4*)(wp);
        float4 w1 = *(const float4*)(wp + 4);
        float4 w2 = *(const float4*)(wp + 8);
        float4 w3 = *(const float4*)(wp + 12);
        bf16x8 p0, p1;
        p0[0]=f2bs(w0.x); p0[1]=f2bs(w0.y); p0[2]=f2bs(w0.z); p0[3]=f2bs(w0.w);
        p0[4]=f2bs(w1.x); p0[5]=f2bs(w1.y); p0[6]=f2bs(w1.z); p0[7]=f2bs(w1.w);
        p1[0]=f2bs(w2.x); p1[1]=f2bs(w2.y); p1[2]=f2bs(w2.z); p1[3]=f2bs(w2.w);
        p1[4]=f2bs(w3.x); p1[5]=f2bs(w3.y); p1[6]=f2bs(w3.z); p1[7]=f2bs(w3.w);
        *(bf16x8*)&sW[((q4 * 2) * 65 + d) * 8]     = p0;
        *(bf16x8*)&sW[((q4 * 2 + 1) * 65 + d) * 8] = p1;
    }
    __syncthreads();

    bf16x8 bfrag[2][4];
#pragma unroll
    for (int s = 0; s < 2; s++)
#pragma unroll
        for (int nt = 0; nt < 4; nt++)
            bfrag[s][nt] = *(const bf16x8*)&sW[((s * 4 + kg) * 65 + nt * 16 + lr) * 8];

    const short* Q = (const short*)qb;
    short* O = (short*)qek;
    int m0 = (mg * 4 + w) * 16;
    bf16x8 a0 = *(const bf16x8*)(Q + (size_t)(m0 + lr) * HH + h * DHEAD + kg * 8);
    bf16x8 a1 = *(const bf16x8*)(Q + (size_t)(m0 + lr) * HH + h * DHEAD + 32 + kg * 8);
#pragma unroll
    for (int nt = 0; nt < 4; nt++) {
        f32x4 acc = (f32x4){0.f, 0.f, 0.f, 0.f};
        acc = __builtin_amdgcn_mfma_f32_16x16x32_bf16(a0, bfrag[0][nt], acc, 0, 0, 0);
        acc = __builtin_amdgcn_mfma_f32_16x16x32_bf16(a1, bfrag[1][nt], acc, 0, 0, 0);
        int row0 = m0 + kg * 4;
#pragma unroll
        for (int r = 0; r < 4; r++)
            O[(size_t)(row0 + r) * HH + h * DHEAD + nt * 16 + lr] = f2bs(acc[r]);
    }
}

// ---------------- escore_add2 (R14-proven) -----------------------------------
__global__ __launch_bounds__(256) void escore_add2(
    const float* __restrict__ edge, const __hip_bfloat16* __restrict__ qek,
    _Float16* __restrict__ sc)
{
    int task = blockIdx.x * 4 + (threadIdx.x >> 6);   // 0..6399
    int l = threadIdx.x & 63;
    int bi = task / 5, seg = task - (task / 5) * 5;
    int lr = l & 15, kg = l >> 4;

    const short* QE = (const short*)qek + (size_t)bi * HH;
    bf16x8 qe0 = *(const bf16x8*)(QE + lr * DHEAD + kg * 8);
    bf16x8 qe1 = *(const bf16x8*)(QE + lr * DHEAD + 32 + kg * 8);

    const float* E = edge + (size_t)bi * SS * DEPTH;
    _Float16* srow = sc + (size_t)bi * SCROW;

#pragma unroll
    for (int t = 0; t < 2; t++) {
        int jt = seg * 2 + t;
        const float* ep = E + (size_t)(jt * 16 + lr) * DEPTH + kg * 8;
        float4 e0 = *(const float4*)(ep);
        float4 e1 = *(const float4*)(ep + 4);
        float4 e2 = *(const float4*)(ep + 32);
        float4 e3 = *(const float4*)(ep + 36);
        bf16x8 a0, a1;
        a0[0]=f2bs(e0.x); a0[1]=f2bs(e0.y); a0[2]=f2bs(e0.z); a0[3]=f2bs(e0.w);
        a0[4]=f2bs(e1.x); a0[5]=f2bs(e1.y); a0[6]=f2bs(e1.z); a0[7]=f2bs(e1.w);
        a1[0]=f2bs(e2.x); a1[1]=f2bs(e2.y); a1[2]=f2bs(e2.z); a1[3]=f2bs(e2.w);
        a1[4]=f2bs(e3.x); a1[5]=f2bs(e3.y); a1[6]=f2bs(e3.z); a1[7]=f2bs(e3.w);
        f32x4 acc = (f32x4){0.f, 0.f, 0.f, 0.f};
        acc = __builtin_amdgcn_mfma_f32_16x16x32_bf16(a0, qe0, acc, 0, 0, 0);
        acc = __builtin_amdgcn_mfma_f32_16x16x32_bf16(a1, qe1, acc, 0, 0, 0);
        if (lr < NHEAD) {
            int j0 = jt * 16 + kg * 4;
            _Float16* p = srow + (size_t)lr * SS + j0;
#pragma unroll
            for (int r = 0; r < 4; r++)
                p[r] = (_Float16)((float)p[r] + 0.125f * acc[r]);
        }
    }
}

// ---------------- pv_soft: per (b,h,itile of 32): softmax + PV MFMA ---------
// Writes probs (f16) back into sc IN PLACE (disjoint slots per block) and
// ctx_v bf16. Grid 480 blocks, LDS ~32 KB.
__global__ __launch_bounds__(256) void pv_soft(
    const __hip_bfloat16* __restrict__ qb, const __hip_bfloat16* __restrict__ vb,
    const float* __restrict__ bek, const int* __restrict__ mask,
    _Float16* __restrict__ sc, __hip_bfloat16* __restrict__ ctxv)
{
    __shared__ alignas(16) short sS[32][168];      // scores f16 -> probs bf16
    __shared__ alignas(16) short sVT[DHEAD][168];  // V^T bf16
    __shared__ float s_qb[32];
    int h = blockIdx.x, b = blockIdx.y, i0 = blockIdx.z * 32;
    int tid = threadIdx.x, w = tid >> 6, l = tid & 63;
    int lr = l & 15, kg = l >> 4;

    // qbek per row (vectorized serial dot, 32 threads)
    if (tid < 32) {
        const short* qp = (const short*)qb + (size_t)(b * SS + i0 + tid) * HH + h * DHEAD;
        const float* bp = bek + h * DHEAD;
        float s = 0.f;
#pragma unroll
        for (int c = 0; c < DHEAD; c += 8) {
            bf16x8 qv = *(const bf16x8*)(qp + c);
            float4 b0 = *(const float4*)(bp + c);
            float4 b1 = *(const float4*)(bp + c + 4);
            union { short s; __hip_bfloat16 b; } u;
            u.s = qv[0]; s += __bfloat162float(u.b) * b0.x;
            u.s = qv[1]; s += __bfloat162float(u.b) * b0.y;
            u.s = qv[2]; s += __bfloat162float(u.b) * b0.z;
            u.s = qv[3]; s += __bfloat162float(u.b) * b0.w;
            u.s = qv[4]; s += __bfloat162float(u.b) * b1.x;
            u.s = qv[5]; s += __bfloat162float(u.b) * b1.y;
            u.s = qv[6]; s += __bfloat162float(u.b) * b1.z;
            u.s = qv[7]; s += __bfloat162float(u.b) * b1.w;
        }
        s_qb[tid] = s;
    }
    // stage V^T
    const short* V = (const short*)vb;
    for (int idx = tid; idx < SS * DHEAD; idx += 256) {
        int j = idx >> 6, c = idx & 63;
        sVT[c][j] = V[(size_t)(b * SS + j) * HH + h * DHEAD + c];
    }
    __syncthreads();

    // stage masked scores as f16
    const int* mbase = mask + (size_t)b * SS * SS + (size_t)i0 * SS;
    for (int idx = tid; idx < 32 * SS; idx += 256) {
        int i = idx / SS, j = idx - i * SS;
        float s = mbase[i * SS + j]
                ? ((float)sc[(size_t)(b * SS + i0 + i) * SCROW + h * SS + j]
                   + 0.125f * s_qb[i])
                : -10000.f;
        _Float16 hv = (_Float16)s;
        sS[i][j] = *(short*)&hv;
    }
    __syncthreads();

    // row softmax; write probs: bf16 to LDS (for PV), f16 to sc (for final_ln)
    for (int r = w; r < 32; r += 4) {
        _Float16* row = (_Float16*)&sS[r][0];
        _Float16* scg = sc + (size_t)(b * SS + i0 + r) * SCROW + h * SS;
        float v0 = (float)row[l];
        float v1 = (float)row[l + 64];
        float v2 = (l < 32) ? (float)row[l + 128] : -INFINITY;
        float mx = fmaxf(v0, fmaxf(v1, v2));
#pragma unroll
        for (int mm = 32; mm >= 1; mm >>= 1) mx = fmaxf(mx, __shfl_xor(mx, mm, 64));
        float e0 = expf(v0 - mx), e1 = expf(v1 - mx);
        float e2 = (l < 32) ? expf(v2 - mx) : 0.f;
        float sm = e0 + e1 + e2;
#pragma unroll
        for (int mm = 32; mm >= 1; mm >>= 1) sm += __shfl_xor(sm, mm, 64);
        float inv = 1.0f / sm;
        float p0 = e0 * inv, p1 = e1 * inv;
        sS[r][l]      = f2bs(p0);
        sS[r][l + 64] = f2bs(p1);
        scg[l]      = (_Float16)p0;
        scg[l + 64] = (_Float16)p1;
        if (l < 32) {
            float p2 = e2 * inv;
            sS[r][l + 128] = f2bs(p2);
            scg[l + 128] = (_Float16)p2;
        }
    }
    __syncthreads();

    // PV MFMA: wave (2x2): M=16(i), N=32(c); K=160 in 5 steps
    int wm = (w >> 1) * 16, wn = (w & 1) * 32;
    f32x4 acc[2];
    acc[0] = (f32x4){0.f, 0.f, 0.f, 0.f};
    acc[1] = (f32x4){0.f, 0.f, 0.f, 0.f};
#pragma unroll
    for (int s = 0; s < 5; s++) {
        int k0 = s * 32 + kg * 8;
        bf16x8 a  = *(const bf16x8*)&sS[wm + lr][k0];
        bf16x8 b0 = *(const bf16x8*)&sVT[wn + lr][k0];
        bf16x8 b1 = *(const bf16x8*)&sVT[wn + 16 + lr][k0];
        acc[0] = __builtin_amdgcn_mfma_f32_16x16x32_bf16(a, b0, acc[0], 0, 0, 0);
        acc[1] = __builtin_amdgcn_mfma_f32_16x16x32_bf16(a, b1, acc[1], 0, 0, 0);
    }

    short* cv = (short*)ctxv;
    int rg = kg * 4;
#pragma unroll
    for (int ni = 0; ni < 2; ni++) {
        int c = wn + ni * 16 + lr;
        f32x4 a = acc[ni];
#pragma unroll
        for (int r = 0; r < 4; r++)
            cv[(size_t)(b * SS + i0 + wm + rg + r) * HH + h * DHEAD + c] = f2bs(a[r]);
    }
}

// ---------------- final_ln: per (b,i): pe = P@E (MFMA) + Wev + LN -----------
// P read from sc (already softmaxed by pv_soft). No mask/qbek/softmax here.
__global__ __launch_bounds__(256) void final_ln(
    const float* __restrict__ token, const float* __restrict__ edge,
    const _Float16* __restrict__ sc, const __hip_bfloat16* __restrict__ ctxv,
    const float* __restrict__ Wev, const float* __restrict__ bev,
    const float* __restrict__ ln_g, const float* __restrict__ ln_b,
    float* __restrict__ out)
{
    __shared__ alignas(16) short sP[16][168];  // probs bf16, rows 12-15 zero
    __shared__ float s_pe[NHEAD][DEPTH];
    __shared__ float s_x[HH];
    __shared__ float s_red[8];

    int bi = blockIdx.x;
    int tid = threadIdx.x;
    int w = tid >> 6, l = tid & 63;
    int lr = l & 15, kg = l >> 4;

    // stage P: linear coalesced f16 reads -> bf16 LDS; zero pad rows
    const _Float16* scrow = sc + (size_t)bi * SCROW;
    for (int idx = tid; idx < 16 * SS; idx += 256) {
        int h = idx / SS, j = idx - h * SS;
        sP[h][j] = (idx < NHEAD * SS) ? f2bs((float)scrow[idx]) : 0;
    }
    __syncthreads();

    // pe[h][d] = sum_j P[h][j] E[j][d]; wave w handles d-tile [w*16, w*16+16)
    {
        const float* Eb = edge + (size_t)bi * SS * DEPTH;
        int d = w * 16 + lr;
        f32x4 acc = (f32x4){0.f, 0.f, 0.f, 0.f};
#pragma unroll
        for (int s = 0; s < 5; s++) {
            int k0 = s * 32 + kg * 8;
            bf16x8 a = *(const bf16x8*)&sP[lr][k0];
            bf16x8 bfr;
#pragma unroll
            for (int e = 0; e < 8; e++)
                bfr[e] = f2bs(Eb[(size_t)(k0 + e) * DEPTH + d]);
            acc = __builtin_amdgcn_mfma_f32_16x16x32_bf16(a, bfr, acc, 0, 0, 0);
        }
#pragma unroll
        for (int r = 0; r < 4; r++) {
            int h = kg * 4 + r;
            if (h < NHEAD) s_pe[h][d] = acc[r];
        }
    }
    __syncthreads();

    // ctx_e = pe_h @ Wev_h + bev ; + ctx_v + token -> s_x
    for (int mdx = tid; mdx < HH; mdx += 256) {
        int h = mdx >> 6;
        const float* pep = &s_pe[h][0];
        float sum = 0.f;
#pragma unroll
        for (int d = 0; d < DEPTH; d++) sum += pep[d] * Wev[(size_t)d * HH + mdx];
        float cvv = __bfloat162float(ctxv[(size_t)bi * HH + mdx]);
        s_x[mdx] = token[(size_t)bi * HH + mdx] + cvv + sum + bev[mdx];
    }
    __syncthreads();

    // LayerNorm
    float lsum = 0.f, lsq = 0.f;
    for (int c = tid; c < HH; c += 256) {
        float x = s_x[c];
        lsum += x; lsq += x * x;
    }
#pragma unroll
    for (int mm = 32; mm >= 1; mm >>= 1) {
        lsum += __shfl_xor(lsum, mm, 64);
        lsq  += __shfl_xor(lsq,  mm, 64);
    }
    if (l == 0) { s_red[w] = lsum; s_red[4 + w] = lsq; }
    __syncthreads();
    float tsum = s_red[0] + s_red[1] + s_red[2] + s_red[3];
    float tsq  = s_red[4] + s_red[5] + s_red[6] + s_red[7];
    float mu  = tsum / HH;
    float var = tsq / HH - mu * mu;
    float rstd = rsqrtf(var + EPS_C);
    for (int c = tid; c < HH; c += 256)
        out[(size_t)bi * HH + c] = (s_x[c] - mu) * rstd * ln_g[c] + ln_b[c];
}

extern "C" void kernel_launch(void* const* d_in, const int* in_sizes, int n_in,
                              void* d_out, int out_size, void* d_ws, size_t ws_size,
                              hipStream_t stream) {
    const float* token = (const float*)d_in[0];
    const float* edge  = (const float*)d_in[1];
    const int*   mask  = (const int*)d_in[2];
    const float* Wq = (const float*)d_in[3];  const float* bq = (const float*)d_in[4];
    const float* Wk = (const float*)d_in[5];  const float* bk = (const float*)d_in[6];
    const float* Wv = (const float*)d_in[7];  const float* bv = (const float*)d_in[8];
    const float* Wek = (const float*)d_in[9];  const float* bek = (const float*)d_in[10];
    const float* Wev = (const float*)d_in[11]; const float* bev = (const float*)d_in[12];
    const float* ln_g = (const float*)d_in[13]; const float* ln_b = (const float*)d_in[14];
    float* out = (float*)d_out;

    // ws layout (10.31 MiB, proven): [qb][kb][vb][sc]
    // qek (1.875 MiB) aliases kb after scores_gemm (kb dead then);
    // ctxv bf16 aliases the same region after escore_add2 (qek dead).
    __hip_bfloat16* qb = (__hip_bfloat16*)d_ws;
    __hip_bfloat16* kb = qb + (size_t)BS * HH;
    __hip_bfloat16* vb = kb + (size_t)BS * HH;
    _Float16*       sc = (_Float16*)(vb + (size_t)BS * HH);
    __hip_bfloat16* qek  = kb;
    __hip_bfloat16* ctxv = kb;

    gemm_qkv<<<dim3(BS / 128, HH / 64, 3), 256, 0, stream>>>(
        token, Wq, Wk, Wv, bq, bk, bv, qb, kb, vb);
    scores_gemm<<<dim3(NHEAD, BB), 256, 0, stream>>>(qb, kb, sc);
    qek_slim<<<dim3(NHEAD, 20), 256, 0, stream>>>(qb, Wek, qek);
    escore_add2<<<1600, 256, 0, stream>>>(edge, qek, sc);
    pv_soft<<<dim3(NHEAD, BB, 5), 256, 0, stream>>>(qb, vb, bek, mask, sc, ctxv);
    final_ln<<<BS, 256, 0, stream>>>(token, edge, sc, ctxv,
                                     Wev, bev, ln_g, ln_b, out);
}